// Round 1
// baseline (26288.162 us; speedup 1.0000x reference)
//
#include <hip/hip_runtime.h>
#include <hip/hip_bf16.h>

typedef short bf16x8 __attribute__((ext_vector_type(8)));
typedef float f32x4  __attribute__((ext_vector_type(4)));

#define S_LEN 512
#define BATCH 64
#define EDIM  512
#define HDIM  512

// ws layout
#define XBF_BYTES   (512u * 64u * 512u * 2u)        // 33,554,432  x_bf[t][b][e] bf16
#define APRE_BYTES  (2u * 32u * 4u * 32u * 64u * 8u * 2u) // 8,388,608 prepacked A-frags
#define HBUF_BYTES  (2u * 2u * 64u * 512u * 2u)     // 262,144  h[dir][parity][b][u] bf16
#define FLAGS_BYTES 1024u

__device__ __forceinline__ unsigned short f2bf(float f) {
  __hip_bfloat16 h = __float2bfloat16(f);
  return *reinterpret_cast<unsigned short*>(&h);
}

__device__ __forceinline__ float sigf(float x)   { return 1.0f / (1.0f + __expf(-x)); }
__device__ __forceinline__ float tanhf_(float x) { return 2.0f / (1.0f + __expf(-2.0f * x)) - 1.0f; }

// x_bf[t][b][:] = bf16(emb[tokens[b][t]][:])
__global__ void gather_kernel(const int* __restrict__ tokens, const float* __restrict__ emb,
                              unsigned short* __restrict__ xbf) {
  int blk = blockIdx.x;             // t*64 + b
  int b = blk & 63, t = blk >> 6;
  int tk = tokens[b * S_LEN + t];
  const float* src = emb + (size_t)tk * EDIM;
  unsigned short* dst = xbf + (size_t)blk * EDIM;
  int e = threadIdx.x * 2;
  float2 v = *reinterpret_cast<const float2*>(src + e);
  unsigned short o0 = f2bf(v.x), o1 = f2bf(v.y);
  unsigned int packed = (unsigned int)o0 | ((unsigned int)o1 << 16);
  *reinterpret_cast<unsigned int*>(dst + e) = packed;
}

// Pre-transpose [W;U] (f32 row-major [k][2048]) into per-wave MFMA A-fragment order (bf16).
// Apre flat index = ((((dir*32+ug)*4+w)*32+kc)*64+lane)*8 + e
// holds Wcat[k = kc*32 + (lane>>4)*8 + e][col], col = (r&3)*512 + ug*16 + w*4 + (r>>2), r = lane&15
__global__ void wprep_kernel(const float* __restrict__ Wf, const float* __restrict__ Uf,
                             const float* __restrict__ Wb, const float* __restrict__ Ub,
                             unsigned short* __restrict__ Apre) {
  int gid = blockIdx.x * 256 + threadIdx.x;   // [0, 524288)
  int lane = gid & 63;
  int kc   = (gid >> 6) & 31;
  int w    = (gid >> 11) & 3;
  int ug   = (gid >> 13) & 31;
  int dir  = (gid >> 18) & 1;
  int r  = lane & 15;
  int hi = (lane >> 4) & 3;
  int k0 = kc * 32 + hi * 8;
  int unit = ug * 16 + w * 4 + (r >> 2);
  int col  = (r & 3) * 512 + unit;
  const float* Wp = dir ? Wb : Wf;
  const float* Up = dir ? Ub : Uf;
  const float* src = (k0 < 512) ? (Wp + (size_t)k0 * 2048 + col)
                                : (Up + (size_t)(k0 - 512) * 2048 + col);
  bf16x8 ov;
#pragma unroll
  for (int e = 0; e < 8; ++e) ov[e] = (short)f2bf(src[(size_t)e * 2048]);
  *reinterpret_cast<bf16x8*>(Apre + (size_t)gid * 8) = ov;
}

// Persistent scan: 256 blocks x 256 threads. Block = (dir, batch-group, 16-unit group).
// Wave w owns units [ug*16 + w*4, +4), computes C[16 gate-rows, 16 batches] via MFMA,
// lane (hi,lo): batch = bg*16+lo, unit = ug*16 + w*4 + hi, acc regs = {i,f,g,o}.
__launch_bounds__(256, 1)
__global__ void scan_kernel(const unsigned short* __restrict__ xbf,
                            const unsigned short* __restrict__ Apre,
                            const float* __restrict__ bfv, const float* __restrict__ bbv,
                            float* __restrict__ out, unsigned short* __restrict__ hbuf,
                            unsigned* __restrict__ flags) {
  int blk = blockIdx.x;
  int g   = blk & 7;        // group = (dir, bg); members share XCD under %8 round-robin
  int dir = g & 1;
  int bg  = (g >> 1) & 3;
  int ug  = blk >> 3;       // 0..31
  int tid  = threadIdx.x;
  int w    = tid >> 6;
  int lane = tid & 63;
  int lo = lane & 15, hi = lane >> 4;
  int unit  = ug * 16 + w * 4 + hi;
  int batch = bg * 16 + lo;

  // preload A fragments: 32 x (8 bf16) = 128 VGPRs, resident for the whole scan
  const unsigned short* abase =
      Apre + ((size_t)(((dir * 32 + ug) * 4 + w) * 32) * 64 + lane) * 8;
  bf16x8 afrag[32];
#pragma unroll
  for (int kc = 0; kc < 32; ++kc)
    afrag[kc] = *reinterpret_cast<const bf16x8*>(abase + (size_t)kc * 512);

  const float* bv = dir ? bbv : bfv;
  f32x4 binit;
  binit[0] = bv[0 * 512 + unit];
  binit[1] = bv[1 * 512 + unit];
  binit[2] = bv[2 * 512 + unit];
  binit[3] = bv[3 * 512 + unit];

  float c = 0.0f;
  unsigned* gflags = flags + g * 32;

  for (int t = 0; t < S_LEN; ++t) {
    int s = dir ? (S_LEN - 1 - t) : t;
    // ---- x part (independent of h_t, runs before the wait) ----
    const unsigned short* xrow = xbf + ((size_t)(s * BATCH + batch) << 9) + (hi << 3);
    f32x4 a0 = binit;
    f32x4 a1 = {0.f, 0.f, 0.f, 0.f};
#pragma unroll
    for (int kc = 0; kc < 16; kc += 2) {
      bf16x8 b0 = *reinterpret_cast<const bf16x8*>(xrow + (kc << 5));
      bf16x8 b1 = *reinterpret_cast<const bf16x8*>(xrow + ((kc + 1) << 5));
      a0 = __builtin_amdgcn_mfma_f32_16x16x32_bf16(afrag[kc],     b0, a0, 0, 0, 0);
      a1 = __builtin_amdgcn_mfma_f32_16x16x32_bf16(afrag[kc + 1], b1, a1, 0, 0, 0);
    }
    // ---- wait for all 32 producer CUs of this group to have published h_t ----
    if (t > 0) {
      if (w == 0) {
        unsigned tv = (unsigned)t;
        unsigned v;
        do {
          v = __hip_atomic_load(gflags + (lane & 31), __ATOMIC_RELAXED,
                                __HIP_MEMORY_SCOPE_AGENT);
        } while (!__all((int)(v >= tv)));
      }
      __syncthreads();
      __threadfence();  // acquire: invalidate L1 so h loads are fresh
    }
    // ---- h part ----
    const unsigned short* hrow =
        hbuf + ((size_t)((dir * 2 + (t & 1)) * BATCH + batch) << 9) + (hi << 3);
    f32x4 a2 = {0.f, 0.f, 0.f, 0.f}, a3 = {0.f, 0.f, 0.f, 0.f};
#pragma unroll
    for (int kc = 0; kc < 16; kc += 2) {
      bf16x8 b0 = *reinterpret_cast<const bf16x8*>(hrow + (kc << 5));
      bf16x8 b1 = *reinterpret_cast<const bf16x8*>(hrow + ((kc + 1) << 5));
      a2 = __builtin_amdgcn_mfma_f32_16x16x32_bf16(afrag[16 + kc],     b0, a2, 0, 0, 0);
      a3 = __builtin_amdgcn_mfma_f32_16x16x32_bf16(afrag[16 + kc + 1], b1, a3, 0, 0, 0);
    }
    // ---- gates (lane-local: regs 0..3 = i,f,g,o of (batch,unit)) ----
    f32x4 z = (a0 + a1) + (a2 + a3);
    float gi = sigf(z[0]);
    float gf = sigf(z[1]);
    float gg = tanhf_(z[2]);
    float go = sigf(z[3]);
    c = gf * c + gi * gg;
    float h = go * tanhf_(c);
    // output (f32, full precision)
    out[(size_t)(batch * S_LEN + s) * 1024 + dir * 512 + unit] = h;
    // recurrence broadcast (bf16, double-buffered parity (t+1)&1)
    hbuf[((size_t)((dir * 2 + ((t + 1) & 1)) * BATCH + batch) << 9) + unit] = f2bf(h);
    // ---- publish ----
    if (t < S_LEN - 1) {
      __threadfence();        // release: drain this thread's stores
      __syncthreads();
      if (tid == 0)
        __hip_atomic_store(gflags + ug, (unsigned)(t + 1), __ATOMIC_RELEASE,
                           __HIP_MEMORY_SCOPE_AGENT);
    }
  }
}

extern "C" void kernel_launch(void* const* d_in, const int* in_sizes, int n_in,
                              void* d_out, int out_size, void* d_ws, size_t ws_size,
                              hipStream_t stream) {
  (void)in_sizes; (void)n_in; (void)out_size; (void)ws_size;
  const int*   tokens = (const int*)d_in[0];
  const float* emb    = (const float*)d_in[1];
  const float* Wf     = (const float*)d_in[2];
  const float* Uf     = (const float*)d_in[3];
  const float* bfv    = (const float*)d_in[4];
  const float* Wb     = (const float*)d_in[5];
  const float* Ub     = (const float*)d_in[6];
  const float* bbv    = (const float*)d_in[7];
  float* out = (float*)d_out;

  char* ws = (char*)d_ws;
  unsigned short* xbf  = (unsigned short*)ws;
  unsigned short* Apre = (unsigned short*)(ws + XBF_BYTES);
  unsigned short* hbuf = (unsigned short*)(ws + XBF_BYTES + APRE_BYTES);
  unsigned*       flags = (unsigned*)(ws + XBF_BYTES + APRE_BYTES + HBUF_BYTES);

  // zero h0 buffers + sync flags (re-done every call; ws is re-poisoned by harness)
  hipMemsetAsync(ws + XBF_BYTES + APRE_BYTES, 0, HBUF_BYTES + FLAGS_BYTES, stream);

  gather_kernel<<<S_LEN * BATCH, 256, 0, stream>>>(tokens, emb, xbf);
  wprep_kernel<<<2048, 256, 0, stream>>>(Wf, Uf, Wb, Ub, Apre);
  scan_kernel<<<256, 256, 0, stream>>>(xbf, Apre, bfv, bbv, out, hbuf, flags);
}

// Round 2
// 3134.579 us; speedup vs baseline: 8.3865x; 8.3865x over previous
//
#include <hip/hip_runtime.h>
#include <hip/hip_bf16.h>

typedef short bf16x8 __attribute__((ext_vector_type(8)));
typedef float f32x4  __attribute__((ext_vector_type(4)));

#define S_LEN 512
#define BATCH 64
#define EDIM  512
#define HDIM  512

// ws layout
#define XBF_BYTES   (512u * 64u * 512u * 2u)        // 33,554,432  x_bf[t][b][e] bf16
#define APRE_BYTES  (2u * 32u * 4u * 32u * 64u * 8u * 2u) // 8,388,608 prepacked A-frags
#define HBUF_BYTES  (2u * 2u * 64u * 512u * 2u)     // 262,144  h[dir][parity][b][u] bf16
#define FLAGS_BYTES 1024u

__device__ __forceinline__ unsigned short f2bf(float f) {
  __hip_bfloat16 h = __float2bfloat16(f);
  return *reinterpret_cast<unsigned short*>(&h);
}

__device__ __forceinline__ float sigf(float x)   { return 1.0f / (1.0f + __expf(-x)); }
__device__ __forceinline__ float tanhf_(float x) { return 2.0f / (1.0f + __expf(-2.0f * x)) - 1.0f; }

// x_bf[t][b][:] = bf16(emb[tokens[b][t]][:])
__global__ void gather_kernel(const int* __restrict__ tokens, const float* __restrict__ emb,
                              unsigned short* __restrict__ xbf) {
  int blk = blockIdx.x;             // t*64 + b
  int b = blk & 63, t = blk >> 6;
  int tk = tokens[b * S_LEN + t];
  const float* src = emb + (size_t)tk * EDIM;
  unsigned short* dst = xbf + (size_t)blk * EDIM;
  int e = threadIdx.x * 2;
  float2 v = *reinterpret_cast<const float2*>(src + e);
  unsigned short o0 = f2bf(v.x), o1 = f2bf(v.y);
  unsigned int packed = (unsigned int)o0 | ((unsigned int)o1 << 16);
  *reinterpret_cast<unsigned int*>(dst + e) = packed;
}

// Pre-transpose [W;U] (f32 row-major [k][2048]) into per-wave MFMA A-fragment order (bf16).
// Apre flat index = ((((dir*32+ug)*4+w)*32+kc)*64+lane)*8 + e
// holds Wcat[k = kc*32 + (lane>>4)*8 + e][col], col = (r&3)*512 + ug*16 + w*4 + (r>>2), r = lane&15
__global__ void wprep_kernel(const float* __restrict__ Wf, const float* __restrict__ Uf,
                             const float* __restrict__ Wb, const float* __restrict__ Ub,
                             unsigned short* __restrict__ Apre) {
  int gid = blockIdx.x * 256 + threadIdx.x;   // [0, 524288)
  int lane = gid & 63;
  int kc   = (gid >> 6) & 31;
  int w    = (gid >> 11) & 3;
  int ug   = (gid >> 13) & 31;
  int dir  = (gid >> 18) & 1;
  int r  = lane & 15;
  int hi = (lane >> 4) & 3;
  int k0 = kc * 32 + hi * 8;
  int unit = ug * 16 + w * 4 + (r >> 2);
  int col  = (r & 3) * 512 + unit;
  const float* Wp = dir ? Wb : Wf;
  const float* Up = dir ? Ub : Uf;
  const float* src = (k0 < 512) ? (Wp + (size_t)k0 * 2048 + col)
                                : (Up + (size_t)(k0 - 512) * 2048 + col);
  bf16x8 ov;
#pragma unroll
  for (int e = 0; e < 8; ++e) ov[e] = (short)f2bf(src[(size_t)e * 2048]);
  *reinterpret_cast<bf16x8*>(Apre + (size_t)gid * 8) = ov;
}

// Persistent scan: 256 blocks x 256 threads. Block = (dir, batch-group, 16-unit group).
// Cross-CU h exchange goes through the device coherence point via sc0/sc1 bypass
// loads/stores — NO fences (no per-step L2 writeback/invalidate).
__launch_bounds__(256, 1)
__global__ void scan_kernel(const unsigned short* __restrict__ xbf,
                            const unsigned short* __restrict__ Apre,
                            const float* __restrict__ bfv, const float* __restrict__ bbv,
                            float* __restrict__ out, unsigned short* __restrict__ hbuf,
                            unsigned* __restrict__ flags) {
  int blk = blockIdx.x;
  int g   = blk & 7;        // group = (dir, bg)
  int dir = g & 1;
  int bg  = (g >> 1) & 3;
  int ug  = blk >> 3;       // 0..31
  int tid  = threadIdx.x;
  int w    = tid >> 6;
  int lane = tid & 63;
  int lo = lane & 15, hi = lane >> 4;
  int unit  = ug * 16 + w * 4 + hi;
  int batch = bg * 16 + lo;

  // preload A fragments: 32 x (8 bf16) = 128 VGPRs, pinned resident for the whole scan
  const unsigned short* abase =
      Apre + ((size_t)(((dir * 32 + ug) * 4 + w) * 32) * 64 + lane) * 8;
  bf16x8 afrag[32];
#pragma unroll
  for (int kc = 0; kc < 32; ++kc)
    afrag[kc] = *reinterpret_cast<const bf16x8*>(abase + (size_t)kc * 512);
  // pin: asm outputs can't be rematerialized -> compiler must keep these in VGPRs
#pragma unroll
  for (int kc = 0; kc < 32; ++kc)
    asm volatile("" : "+v"(afrag[kc]));

  const float* bv = dir ? bbv : bfv;
  f32x4 binit;
  binit[0] = bv[0 * 512 + unit];
  binit[1] = bv[1 * 512 + unit];
  binit[2] = bv[2 * 512 + unit];
  binit[3] = bv[3 * 512 + unit];

  float c = 0.0f;
  unsigned* gflags = flags + g * 32;

  for (int t = 0; t < S_LEN; ++t) {
    int s = dir ? (S_LEN - 1 - t) : t;
    // ---- x part (independent of h_t, runs before the wait; cached loads) ----
    const unsigned short* xrow = xbf + ((size_t)(s * BATCH + batch) << 9) + (hi << 3);
    f32x4 a0 = binit;
    f32x4 a1 = {0.f, 0.f, 0.f, 0.f};
#pragma unroll
    for (int kc = 0; kc < 16; kc += 2) {
      bf16x8 b0 = *reinterpret_cast<const bf16x8*>(xrow + (kc << 5));
      bf16x8 b1 = *reinterpret_cast<const bf16x8*>(xrow + ((kc + 1) << 5));
      a0 = __builtin_amdgcn_mfma_f32_16x16x32_bf16(afrag[kc],     b0, a0, 0, 0, 0);
      a1 = __builtin_amdgcn_mfma_f32_16x16x32_bf16(afrag[kc + 1], b1, a1, 0, 0, 0);
    }
    // ---- wait for all 32 producer CUs of this group (relaxed agent polls, no fence) ----
    if (t > 0) {
      if (w == 0) {
        unsigned tv = (unsigned)t;
        unsigned v;
        do {
          v = __hip_atomic_load(gflags + (lane & 31), __ATOMIC_RELAXED,
                                __HIP_MEMORY_SCOPE_AGENT);
        } while (__any((int)(v < tv)));
      }
      __syncthreads();
    }
    // ---- h part: coherence-point (sc0 sc1) bypass loads, counted waits ----
    const unsigned short* hrow =
        hbuf + ((size_t)((dir * 2 + (t & 1)) * BATCH + batch) << 9) + (hi << 3);
    bf16x8 hb[16];
#pragma unroll
    for (int kc = 0; kc < 16; ++kc)
      asm volatile("global_load_dwordx4 %0, %1, off offset:%2 sc0 sc1"
                   : "=v"(hb[kc]) : "v"(hrow), "n"(kc * 64));
    f32x4 a2 = {0.f, 0.f, 0.f, 0.f}, a3 = {0.f, 0.f, 0.f, 0.f};
    asm volatile("s_waitcnt vmcnt(8)" ::: "memory");
    __builtin_amdgcn_sched_barrier(0);
#pragma unroll
    for (int kc = 0; kc < 8; kc += 2) {
      a2 = __builtin_amdgcn_mfma_f32_16x16x32_bf16(afrag[16 + kc],     hb[kc],     a2, 0, 0, 0);
      a3 = __builtin_amdgcn_mfma_f32_16x16x32_bf16(afrag[16 + kc + 1], hb[kc + 1], a3, 0, 0, 0);
    }
    asm volatile("s_waitcnt vmcnt(0)" ::: "memory");
    __builtin_amdgcn_sched_barrier(0);
#pragma unroll
    for (int kc = 8; kc < 16; kc += 2) {
      a2 = __builtin_amdgcn_mfma_f32_16x16x32_bf16(afrag[16 + kc],     hb[kc],     a2, 0, 0, 0);
      a3 = __builtin_amdgcn_mfma_f32_16x16x32_bf16(afrag[16 + kc + 1], hb[kc + 1], a3, 0, 0, 0);
    }
    // ---- gates (lane-local: regs 0..3 = i,f,g,o of (batch,unit)) ----
    f32x4 z = (a0 + a1) + (a2 + a3);
    float gi = sigf(z[0]);
    float gf = sigf(z[1]);
    float gg = tanhf_(z[2]);
    float go = sigf(z[3]);
    c = gf * c + gi * gg;
    float h = go * tanhf_(c);
    // recurrence broadcast: bypass store to coherence point (parity (t+1)&1)
    unsigned short hbits = f2bf(h);
    unsigned short* hst =
        hbuf + ((size_t)((dir * 2 + ((t + 1) & 1)) * BATCH + batch) << 9) + unit;
    asm volatile("global_store_short %0, %1, off sc0 sc1"
                 :: "v"(hst), "v"((unsigned)hbits) : "memory");
    // ---- publish: vmcnt(0) is the release guarantee, then one flag store ----
    if (t < S_LEN - 1) {
      asm volatile("s_waitcnt vmcnt(0)" ::: "memory");
      __syncthreads();
      if (tid == 0)
        __hip_atomic_store(gflags + ug, (unsigned)(t + 1), __ATOMIC_RELAXED,
                           __HIP_MEMORY_SCOPE_AGENT);
    }
    // output store AFTER publish: its HBM ack is off the critical path
    out[(size_t)(batch * S_LEN + s) * 1024 + dir * 512 + unit] = h;
  }
}

extern "C" void kernel_launch(void* const* d_in, const int* in_sizes, int n_in,
                              void* d_out, int out_size, void* d_ws, size_t ws_size,
                              hipStream_t stream) {
  (void)in_sizes; (void)n_in; (void)out_size; (void)ws_size;
  const int*   tokens = (const int*)d_in[0];
  const float* emb    = (const float*)d_in[1];
  const float* Wf     = (const float*)d_in[2];
  const float* Uf     = (const float*)d_in[3];
  const float* bfv    = (const float*)d_in[4];
  const float* Wb     = (const float*)d_in[5];
  const float* Ub     = (const float*)d_in[6];
  const float* bbv    = (const float*)d_in[7];
  float* out = (float*)d_out;

  char* ws = (char*)d_ws;
  unsigned short* xbf  = (unsigned short*)ws;
  unsigned short* Apre = (unsigned short*)(ws + XBF_BYTES);
  unsigned short* hbuf = (unsigned short*)(ws + XBF_BYTES + APRE_BYTES);
  unsigned*       flags = (unsigned*)(ws + XBF_BYTES + APRE_BYTES + HBUF_BYTES);

  // zero h0 buffers + sync flags (re-done every call; ws is re-poisoned by harness)
  hipMemsetAsync(ws + XBF_BYTES + APRE_BYTES, 0, HBUF_BYTES + FLAGS_BYTES, stream);

  gather_kernel<<<S_LEN * BATCH, 256, 0, stream>>>(tokens, emb, xbf);
  wprep_kernel<<<2048, 256, 0, stream>>>(Wf, Uf, Wb, Ub, Apre);
  scan_kernel<<<256, 256, 0, stream>>>(xbf, Apre, bfv, bbv, out, hbuf, flags);
}